// Round 4
// baseline (784.904 us; speedup 1.0000x reference)
//
#include <hip/hip_runtime.h>
#include <hip/hip_bf16.h>
#include <math.h>

// GATv2 (2 layers, D=128) + encoders + self-loops + mean-pool + sigmoid readout.
// Pipeline:
//   atom_kernel   : h[n] = sum_f atom_emb[f, x[n,f]]
//   edge_hist     : cnt[dst]++, hist[dst][f,v]++  (sort offsets + self-loop mean attr)
//   scanA/B/C     : off = exclusive_scan(cnt)  (3-phase parallel scan; off[N]=E)
//   scatter_kernel: counting-sort edges by dst; pack (src | 3x3bit attrs) in u32
//   table_kernel  : tab{1,2}[f,v] = bond_emb[f,v] @ W{1,2}e  (2x24x128 — replaces the
//                   E'x128 edge GEMMs, since edge emb is a sum of 3 rows of 8-row
//                   tables and @We is linear; both layers in one 48-block launch)
//   lin2_kernel   : hl = h@Wl+bl, hr = h@Wr+br (fused; 32-row tile, FMA-bound)
//   attn_kernel   : wave-per-node online-softmax GATv2 aggregation, 8-edge
//                   predicated batches (clamped index + score=-inf masking, no tail)
//   pool_kernel   : run-length mean-pool accumulate (batch is sorted)
//   out_kernel    : sigmoid(mean @ Wout + bout)

typedef unsigned int uint;

#define THREADS 256
#define LOG2E 1.4426950408889634f
// edge packing: src in bits [0,23), a0<<23, a1<<26, a2<<29
#define SRC_MASK 0x7fffffu

__global__ void atom_kernel(const int* __restrict__ x, const float* __restrict__ atom_emb,
                            float* __restrict__ h, int n) {
  int idx = blockIdx.x * blockDim.x + threadIdx.x;
  int node = idx >> 7, d = idx & 127;
  if (node >= n) return;
  float s = 0.f;
#pragma unroll
  for (int f = 0; f < 9; f++) {
    int v = x[node * 9 + f];
    s += atom_emb[(f * 128 + v) * 128 + d];
  }
  h[idx] = s;
}

__global__ void edge_hist_kernel(const int* __restrict__ ei, const int* __restrict__ ea,
                                 uint* __restrict__ cnt, uint* __restrict__ hist, int E_) {
  int e = blockIdx.x * blockDim.x + threadIdx.x;
  if (e >= E_) return;
  int dst = ei[E_ + e];
  int a0 = ea[e * 3 + 0], a1 = ea[e * 3 + 1], a2 = ea[e * 3 + 2];
  atomicAdd(&cnt[dst], 1u);
  atomicAdd(&hist[dst * 24 + a0], 1u);
  atomicAdd(&hist[dst * 24 + 8 + a1], 1u);
  atomicAdd(&hist[dst * 24 + 16 + a2], 1u);
}

// ---- 3-phase exclusive scan of cnt[0..n) into off[0..n] ----
__global__ __launch_bounds__(256) void scanA_kernel(const uint* __restrict__ cnt,
                                                    uint* __restrict__ off,
                                                    uint* __restrict__ bsum, int n) {
  __shared__ uint sc[256];
  int t = threadIdx.x;
  int base = blockIdx.x * 1024 + t * 4;
  uint v[4];
#pragma unroll
  for (int i = 0; i < 4; i++) v[i] = (base + i < n) ? cnt[base + i] : 0u;
  uint s = v[0] + v[1] + v[2] + v[3];
  sc[t] = s;
  __syncthreads();
  for (int o = 1; o < 256; o <<= 1) {
    uint w = (t >= o) ? sc[t - o] : 0u;
    __syncthreads();
    sc[t] += w;
    __syncthreads();
  }
  uint excl = sc[t] - s;
  uint r = excl;
#pragma unroll
  for (int i = 0; i < 4; i++) {
    if (base + i < n) off[base + i] = r;
    r += v[i];
  }
  if (t == 255) bsum[blockIdx.x] = sc[t];
}

__global__ __launch_bounds__(256) void scanB_kernel(const uint* __restrict__ bsum,
                                                    uint* __restrict__ bpre, int nb) {
  __shared__ uint sc[256];
  int t = threadIdx.x;
  uint s = (t < nb) ? bsum[t] : 0u;
  sc[t] = s;
  __syncthreads();
  for (int o = 1; o < 256; o <<= 1) {
    uint w = (t >= o) ? sc[t - o] : 0u;
    __syncthreads();
    sc[t] += w;
    __syncthreads();
  }
  if (t < nb) bpre[t] = sc[t] - s;
}

__global__ void scanC_kernel(uint* __restrict__ off, const uint* __restrict__ bpre, int n,
                             int E_) {
  int i = blockIdx.x * blockDim.x + threadIdx.x;
  if (i < n) off[i] += bpre[i >> 10];
  if (i == 0) off[n] = (uint)E_;
}

__global__ void scatter_kernel(const int* __restrict__ ei, const int* __restrict__ ea,
                               const uint* __restrict__ off, uint* __restrict__ fill,
                               uint* __restrict__ sorted, int E_) {
  int e = blockIdx.x * blockDim.x + threadIdx.x;
  if (e >= E_) return;
  int src = ei[e], dst = ei[E_ + e];
  uint pos = off[dst] + atomicAdd(&fill[dst], 1u);
  uint pk = ((uint)src & SRC_MASK) | ((uint)ea[e * 3 + 0] << 23) |
            ((uint)ea[e * 3 + 1] << 26) | ((uint)ea[e * 3 + 2] << 29);
  sorted[pos] = pk;
}

// blocks 0..23: tab1[j] = bond_emb[j] @ W1e ; blocks 24..47: tab2[j-24] = bond_emb[j-24] @ W2e
__global__ void table_kernel(const float* __restrict__ bond_emb, const float* __restrict__ W1e,
                             const float* __restrict__ W2e, float* __restrict__ tab1,
                             float* __restrict__ tab2) {
  __shared__ float row[128];
  int b = blockIdx.x;
  int j = (b < 24) ? b : b - 24;
  const float* We = (b < 24) ? W1e : W2e;
  float* tab = (b < 24) ? tab1 : tab2;
  row[threadIdx.x] = bond_emb[j * 128 + threadIdx.x];
  __syncthreads();
  float acc = 0.f;
#pragma unroll 4
  for (int k = 0; k < 128; k++) acc += row[k] * We[k * 128 + threadIdx.x];
  tab[j * 128 + threadIdx.x] = acc;
}

// hl = h@Wl+bl ; hr = h@Wr+br  — 32-row tile, 256 threads; broadcast LDS reads, FMA-bound
__global__ __launch_bounds__(256) void lin2_kernel(
    const float* __restrict__ h, const float* __restrict__ Wl, const float* __restrict__ bl,
    const float* __restrict__ Wr, const float* __restrict__ br,
    float* __restrict__ hl, float* __restrict__ hr, int n) {
  __shared__ float hs[32][132];  // row stride 528B -> 16B-aligned float4 reads
  int r0 = blockIdx.x * 32;
  for (int i = threadIdx.x; i < 32 * 128; i += 256) {
    int r = i >> 7, c = i & 127;
    int gr = r0 + r;
    hs[r][c] = (gr < n) ? h[gr * 128 + c] : 0.f;
  }
  __syncthreads();
  int col = threadIdx.x & 127;
  int half = threadIdx.x >> 7;  // owns rows half*16 .. half*16+15
  float accl[16], accr[16];
  float bvl = bl[col], bvr = br[col];
#pragma unroll
  for (int i = 0; i < 16; i++) { accl[i] = bvl; accr[i] = bvr; }
  for (int k = 0; k < 128; k += 4) {
    float wl[4], wr[4];
#pragma unroll
    for (int kk = 0; kk < 4; kk++) {
      wl[kk] = Wl[(k + kk) * 128 + col];
      wr[kk] = Wr[(k + kk) * 128 + col];
    }
#pragma unroll
    for (int i = 0; i < 16; i++) {
      float4 hv = *(const float4*)&hs[half * 16 + i][k];
      accl[i] += hv.x * wl[0] + hv.y * wl[1] + hv.z * wl[2] + hv.w * wl[3];
      accr[i] += hv.x * wr[0] + hv.y * wr[1] + hv.z * wr[2] + hv.w * wr[3];
    }
  }
#pragma unroll
  for (int i = 0; i < 16; i++) {
    int gr = r0 + half * 16 + i;
    if (gr < n) {
      hl[gr * 128 + col] = accl[i];
      hr[gr * 128 + col] = accr[i];
    }
  }
}

// One wave per node: online-softmax GATv2 aggregation, 8-edge predicated batches.
__global__ __launch_bounds__(256) void attn_kernel(
    const float* __restrict__ hl, const float* __restrict__ hr,
    const uint* __restrict__ off, const uint* __restrict__ sorted,
    const uint* __restrict__ cnt, const uint* __restrict__ hist,
    const float* __restrict__ tab, const float* __restrict__ att,
    const float* __restrict__ bias, float* __restrict__ out, int n, int do_relu) {
  __shared__ float tabs[24][128];
  __shared__ float atts[128];
  for (int i = threadIdx.x; i < 24 * 128; i += 256) tabs[i >> 7][i & 127] = tab[i];
  if (threadIdx.x < 128) atts[threadIdx.x] = att[threadIdx.x] * LOG2E;  // fold log2e: exp->exp2
  __syncthreads();
  int wave = threadIdx.x >> 6, lane = threadIdx.x & 63;
  int node = blockIdx.x * 4 + wave;
  if (node >= n) return;
  int d = lane * 2;

  float2 hrv = *(const float2*)&hr[node * 128 + d];
  float2 hlo = *(const float2*)&hl[node * 128 + d];
  float2 av = make_float2(atts[d], atts[d + 1]);

  // self-loop edge projection = mean of incoming e_proj, via (feature,value) histogram
  float2 ep = make_float2(0.f, 0.f);
  uint c = cnt[node];
  if (c) {
#pragma unroll
    for (int j = 0; j < 24; j++) {
      float f = (float)hist[node * 24 + j];
      float2 tv = *(const float2*)&tabs[j][d];
      ep.x += f * tv.x;
      ep.y += f * tv.y;
    }
    float inv = 1.0f / (float)c;
    ep.x *= inv;
    ep.y *= inv;
  }

  // score (log2-scaled) = leaky_relu(hl[src]+hr[dst]+ep) . (att*log2e), wave-reduced
  auto score_of = [&](float2 hls, float2 epv) -> float {
    float tx = hls.x + hrv.x + epv.x;
    float ty = hls.y + hrv.y + epv.y;
    tx = tx > 0.f ? tx : 0.2f * tx;
    ty = ty > 0.f ? ty : 0.2f * ty;
    float p = tx * av.x + ty * av.y;
#pragma unroll
    for (int o = 32; o > 0; o >>= 1) p += __shfl_xor(p, o);
    return p;
  };
  auto eproj_of = [&](uint pk) -> float2 {
    int a0 = (pk >> 23) & 7, a1 = (pk >> 26) & 7, a2 = (pk >> 29) & 7;
    float2 t0 = *(const float2*)&tabs[a0][d];
    float2 t1 = *(const float2*)&tabs[8 + a1][d];
    float2 t2 = *(const float2*)&tabs[16 + a2][d];
    return make_float2(t0.x + t1.x + t2.x, t0.y + t1.y + t2.y);
  };

  // init with self-loop
  float m = score_of(hlo, ep);
  float s = 1.0f;
  float2 acc = hlo;

  uint e0 = off[node], e1 = off[node + 1];
  for (uint e = e0; e < e1; e += 8) {
    uint pk[8];
    float2 hv[8];
    float sc[8], p[8];
#pragma unroll
    for (int i = 0; i < 8; i++) {
      uint ee = e + (uint)i;
      pk[i] = sorted[ee < e1 ? ee : e1 - 1];  // clamp: duplicates masked below
    }
#pragma unroll
    for (int i = 0; i < 8; i++) hv[i] = *(const float2*)&hl[(pk[i] & SRC_MASK) * 128 + d];
#pragma unroll
    for (int i = 0; i < 8; i++) sc[i] = score_of(hv[i], eproj_of(pk[i]));
#pragma unroll
    for (int i = 0; i < 8; i++)
      if (e + (uint)i >= e1) sc[i] = -INFINITY;  // exp2(-inf)=0 -> zero weight
    float m8 = sc[0];
#pragma unroll
    for (int i = 1; i < 8; i++) m8 = fmaxf(m8, sc[i]);
    float mn = fmaxf(m, m8);
    float corr = exp2f(m - mn);
#pragma unroll
    for (int i = 0; i < 8; i++) p[i] = exp2f(sc[i] - mn);
    float ps = 0.f;
    float2 pa = make_float2(0.f, 0.f);
#pragma unroll
    for (int i = 0; i < 8; i++) {
      ps += p[i];
      pa.x += p[i] * hv[i].x;
      pa.y += p[i] * hv[i].y;
    }
    s = s * corr + ps;
    acc.x = acc.x * corr + pa.x;
    acc.y = acc.y * corr + pa.y;
    m = mn;
  }

  float inv = 1.0f / s;
  float2 o;
  o.x = acc.x * inv + bias[d];
  o.y = acc.y * inv + bias[d + 1];
  if (do_relu) {
    o.x = fmaxf(o.x, 0.f);
    o.y = fmaxf(o.y, 0.f);
  }
  *(float2*)&out[node * 128 + d] = o;
}

// batch is sorted: run-length accumulate, flush once per graph boundary per block-chunk.
#define POOL_CHUNK 128
__global__ void pool_kernel(const float* __restrict__ h, const int* __restrict__ batch,
                            float* __restrict__ pool, uint* __restrict__ cntg, int n) {
  int d = threadIdx.x;  // 128 threads
  int i0 = blockIdx.x * POOL_CHUNK;
  if (i0 >= n) return;
  int i1 = min(i0 + POOL_CHUNK, n);
  int g = batch[i0];
  float s = 0.f;
  uint c = 0;
  for (int i = i0; i < i1; i++) {
    int gi = batch[i];
    if (gi != g) {
      atomicAdd(&pool[g * 128 + d], s);
      if (d == 0) atomicAdd(&cntg[g], c);
      g = gi;
      s = 0.f;
      c = 0;
    }
    s += h[i * 128 + d];
    c++;
  }
  atomicAdd(&pool[g * 128 + d], s);
  if (d == 0) atomicAdd(&cntg[g], c);
}

__global__ void out_kernel(const float* __restrict__ pool, const uint* __restrict__ cntg,
                           const float* __restrict__ Wout, const float* __restrict__ bout,
                           float* __restrict__ out, int g_) {
  int wave = threadIdx.x >> 6, lane = threadIdx.x & 63;
  int g = blockIdx.x * 4 + wave;
  if (g >= g_) return;
  int d = lane * 2;
  float2 pv = *(const float2*)&pool[g * 128 + d];
  float2 wv = *(const float2*)&Wout[d];
  float p = pv.x * wv.x + pv.y * wv.y;
#pragma unroll
  for (int o = 32; o > 0; o >>= 1) p += __shfl_xor(p, o);
  if (lane == 0) {
    uint c = cntg[g];
    float cf = (float)(c ? c : 1u);
    float v = p / cf + bout[0];
    out[g] = 1.f / (1.f + expf(-v));
  }
}

extern "C" void kernel_launch(void* const* d_in, const int* in_sizes, int n_in,
                              void* d_out, int out_size, void* d_ws, size_t ws_size,
                              hipStream_t stream) {
  const int* x          = (const int*)d_in[0];
  const int* edge_index = (const int*)d_in[1];
  const int* edge_attr  = (const int*)d_in[2];
  const int* batch      = (const int*)d_in[3];
  const float* atom_emb = (const float*)d_in[4];
  const float* bond_emb = (const float*)d_in[5];
  const float* W1l = (const float*)d_in[6];
  const float* b1l = (const float*)d_in[7];
  const float* W1r = (const float*)d_in[8];
  const float* b1r = (const float*)d_in[9];
  const float* W1e = (const float*)d_in[10];
  const float* att1 = (const float*)d_in[11];
  const float* bias1 = (const float*)d_in[12];
  const float* W2l = (const float*)d_in[13];
  const float* b2l = (const float*)d_in[14];
  const float* W2r = (const float*)d_in[15];
  const float* b2r = (const float*)d_in[16];
  const float* W2e = (const float*)d_in[17];
  const float* att2 = (const float*)d_in[18];
  const float* bias2 = (const float*)d_in[19];
  const float* Wout = (const float*)d_in[20];
  const float* bout = (const float*)d_in[21];
  float* out = (float*)d_out;

  const int N = in_sizes[0] / 9;
  const int E = in_sizes[1] / 2;
  const int G = out_size;
  const int NB = (N + 1023) / 1024;  // scan blocks

  // workspace layout (3 big N*128 buffers: attn output overwrites lin2 input)
  char* w = (char*)d_ws;
  auto alloc = [&](size_t bytes) -> char* {
    char* p = w;
    w += (bytes + 255) & ~(size_t)255;
    return p;
  };
  float* h0     = (float*)alloc((size_t)N * 128 * 4);  // atom out / layer outs
  float* hl     = (float*)alloc((size_t)N * 128 * 4);
  float* hr     = (float*)alloc((size_t)N * 128 * 4);
  uint* cnt     = (uint*)alloc((size_t)N * 4);
  uint* off     = (uint*)alloc((size_t)(N + 1) * 4);
  uint* fill    = (uint*)alloc((size_t)N * 4);
  uint* hist    = (uint*)alloc((size_t)N * 24 * 4);
  uint* sorted  = (uint*)alloc((size_t)E * 4);
  float* tab1   = (float*)alloc(24 * 128 * 4);
  float* tab2   = (float*)alloc(24 * 128 * 4);
  float* pool   = (float*)alloc((size_t)G * 128 * 4);
  uint* cntg    = (uint*)alloc((size_t)G * 4);
  uint* bsum    = (uint*)alloc((size_t)NB * 4);
  uint* bpre    = (uint*)alloc((size_t)NB * 4);

  hipMemsetAsync(cnt, 0, (size_t)N * 4, stream);
  hipMemsetAsync(fill, 0, (size_t)N * 4, stream);
  hipMemsetAsync(hist, 0, (size_t)N * 24 * 4, stream);
  hipMemsetAsync(pool, 0, (size_t)G * 128 * 4, stream);
  hipMemsetAsync(cntg, 0, (size_t)G * 4, stream);

  table_kernel<<<48, 128, 0, stream>>>(bond_emb, W1e, W2e, tab1, tab2);
  atom_kernel<<<(N * 128 + THREADS - 1) / THREADS, THREADS, 0, stream>>>(x, atom_emb, h0, N);
  edge_hist_kernel<<<(E + THREADS - 1) / THREADS, THREADS, 0, stream>>>(edge_index, edge_attr,
                                                                        cnt, hist, E);
  scanA_kernel<<<NB, 256, 0, stream>>>(cnt, off, bsum, N);
  scanB_kernel<<<1, 256, 0, stream>>>(bsum, bpre, NB);
  scanC_kernel<<<(N + THREADS - 1) / THREADS, THREADS, 0, stream>>>(off, bpre, N, E);
  scatter_kernel<<<(E + THREADS - 1) / THREADS, THREADS, 0, stream>>>(edge_index, edge_attr, off,
                                                                      fill, sorted, E);
  // layer 1
  lin2_kernel<<<(N + 31) / 32, 256, 0, stream>>>(h0, W1l, b1l, W1r, b1r, hl, hr, N);
  attn_kernel<<<(N + 3) / 4, 256, 0, stream>>>(hl, hr, off, sorted, cnt, hist, tab1, att1, bias1,
                                               h0, N, 1);
  // layer 2
  lin2_kernel<<<(N + 31) / 32, 256, 0, stream>>>(h0, W2l, b2l, W2r, b2r, hl, hr, N);
  attn_kernel<<<(N + 3) / 4, 256, 0, stream>>>(hl, hr, off, sorted, cnt, hist, tab2, att2, bias2,
                                               h0, N, 0);
  // readout
  pool_kernel<<<(N + POOL_CHUNK - 1) / POOL_CHUNK, 128, 0, stream>>>(h0, batch, pool, cntg, N);
  out_kernel<<<(G + 3) / 4, 256, 0, stream>>>(pool, cntg, Wout, bout, out, G);
}

// Round 8
// 727.744 us; speedup vs baseline: 1.0785x; 1.0785x over previous
//
#include <hip/hip_runtime.h>
#include <hip/hip_bf16.h>
#include <math.h>

// GATv2 (2 layers, D=128) + encoders + self-loops + mean-pool + sigmoid readout.
// attn_kernel v2: one wave per node; 4 edge-groups of 16 lanes (8 dims/lane).
// Per-edge score butterfly = 4 levels shared by 4 edges (was 6 levels per edge
// over 64 lanes). Per-group online-softmax states merged at the end (xor16,32).

typedef unsigned int uint;

#define THREADS 256
#define LOG2E 1.4426950408889634f
#define NEGM -1e30f
// edge packing: src in bits [0,23), a0<<23, a1<<26, a2<<29
#define SRC_MASK 0x7fffffu

__device__ inline float4 f4add(float4 x, float4 y) {
  return make_float4(x.x + y.x, x.y + y.y, x.z + y.z, x.w + y.w);
}
__device__ inline float4 f4fma(float c, float4 x, float4 y) {  // c*x + y
  return make_float4(fmaf(c, x.x, y.x), fmaf(c, x.y, y.y), fmaf(c, x.z, y.z),
                     fmaf(c, x.w, y.w));
}
__device__ inline float4 f4scale(float4 x, float c) {
  return make_float4(x.x * c, x.y * c, x.z * c, x.w * c);
}
__device__ inline float lrelu_dot(float4 z, float4 a) {
  float r = (z.x > 0.f ? z.x : 0.2f * z.x) * a.x;
  r += (z.y > 0.f ? z.y : 0.2f * z.y) * a.y;
  r += (z.z > 0.f ? z.z : 0.2f * z.z) * a.z;
  r += (z.w > 0.f ? z.w : 0.2f * z.w) * a.w;
  return r;
}
__device__ inline float4 f4relu(float4 x) {
  return make_float4(fmaxf(x.x, 0.f), fmaxf(x.y, 0.f), fmaxf(x.z, 0.f), fmaxf(x.w, 0.f));
}

__global__ void atom_kernel(const int* __restrict__ x, const float* __restrict__ atom_emb,
                            float* __restrict__ h, int n) {
  int idx = blockIdx.x * blockDim.x + threadIdx.x;
  int node = idx >> 7, d = idx & 127;
  if (node >= n) return;
  float s = 0.f;
#pragma unroll
  for (int f = 0; f < 9; f++) {
    int v = x[node * 9 + f];
    s += atom_emb[(f * 128 + v) * 128 + d];
  }
  h[idx] = s;
}

// hist[dst][f,v]++  (in-degree = sum of the first 8 bins; no separate cnt)
__global__ void edge_hist_kernel(const int* __restrict__ ei, const int* __restrict__ ea,
                                 uint* __restrict__ hist, int E_) {
  int e = blockIdx.x * blockDim.x + threadIdx.x;
  if (e >= E_) return;
  int dst = ei[E_ + e];
  int a0 = ea[e * 3 + 0], a1 = ea[e * 3 + 1], a2 = ea[e * 3 + 2];
  atomicAdd(&hist[dst * 24 + a0], 1u);
  atomicAdd(&hist[dst * 24 + 8 + a1], 1u);
  atomicAdd(&hist[dst * 24 + 16 + a2], 1u);
}

// ---- 3-phase exclusive scan of degree (= sum of hist bins 0..7) into off[0..n] ----
__global__ __launch_bounds__(256) void scanA_kernel(const uint* __restrict__ hist,
                                                    uint* __restrict__ off,
                                                    uint* __restrict__ bsum, int n) {
  __shared__ uint sc[256];
  int t = threadIdx.x;
  int base = blockIdx.x * 1024 + t * 4;
  uint v[4];
#pragma unroll
  for (int i = 0; i < 4; i++) {
    uint d = 0;
    int idx = base + i;
    if (idx < n) {
      const uint4* hp = (const uint4*)&hist[idx * 24];
      uint4 h0 = hp[0], h1 = hp[1];
      d = h0.x + h0.y + h0.z + h0.w + h1.x + h1.y + h1.z + h1.w;
    }
    v[i] = d;
  }
  uint s = v[0] + v[1] + v[2] + v[3];
  sc[t] = s;
  __syncthreads();
  for (int o = 1; o < 256; o <<= 1) {
    uint w = (t >= o) ? sc[t - o] : 0u;
    __syncthreads();
    sc[t] += w;
    __syncthreads();
  }
  uint r = sc[t] - s;
#pragma unroll
  for (int i = 0; i < 4; i++) {
    if (base + i < n) off[base + i] = r;
    r += v[i];
  }
  if (t == 255) bsum[blockIdx.x] = sc[t];
}

__global__ __launch_bounds__(256) void scanB_kernel(const uint* __restrict__ bsum,
                                                    uint* __restrict__ bpre, int nb) {
  __shared__ uint sc[256];
  int t = threadIdx.x;
  uint s = (t < nb) ? bsum[t] : 0u;
  sc[t] = s;
  __syncthreads();
  for (int o = 1; o < 256; o <<= 1) {
    uint w = (t >= o) ? sc[t - o] : 0u;
    __syncthreads();
    sc[t] += w;
    __syncthreads();
  }
  if (t < nb) bpre[t] = sc[t] - s;
}

__global__ void scanC_kernel(uint* __restrict__ off, const uint* __restrict__ bpre, int n,
                             int E_) {
  int i = blockIdx.x * blockDim.x + threadIdx.x;
  if (i < n) off[i] += bpre[i >> 10];
  if (i == 0) off[n] = (uint)E_;
}

__global__ void scatter_kernel(const int* __restrict__ ei, const int* __restrict__ ea,
                               const uint* __restrict__ off, uint* __restrict__ fill,
                               uint* __restrict__ sorted, int E_) {
  int e = blockIdx.x * blockDim.x + threadIdx.x;
  if (e >= E_) return;
  int src = ei[e], dst = ei[E_ + e];
  uint pos = off[dst] + atomicAdd(&fill[dst], 1u);
  uint pk = ((uint)src & SRC_MASK) | ((uint)ea[e * 3 + 0] << 23) |
            ((uint)ea[e * 3 + 1] << 26) | ((uint)ea[e * 3 + 2] << 29);
  sorted[pos] = pk;
}

// blocks 0..23: tab1[j] = bond_emb[j] @ W1e ; blocks 24..47: tab2[j-24] = bond_emb[j-24] @ W2e
__global__ void table_kernel(const float* __restrict__ bond_emb, const float* __restrict__ W1e,
                             const float* __restrict__ W2e, float* __restrict__ tab1,
                             float* __restrict__ tab2) {
  __shared__ float row[128];
  int b = blockIdx.x;
  int j = (b < 24) ? b : b - 24;
  const float* We = (b < 24) ? W1e : W2e;
  float* tab = (b < 24) ? tab1 : tab2;
  row[threadIdx.x] = bond_emb[j * 128 + threadIdx.x];
  __syncthreads();
  float acc = 0.f;
#pragma unroll 4
  for (int k = 0; k < 128; k++) acc += row[k] * We[k * 128 + threadIdx.x];
  tab[j * 128 + threadIdx.x] = acc;
}

// hl = h@Wl+bl ; hr = h@Wr+br  — 32-row tile, 256 threads; broadcast LDS reads, FMA-bound
__global__ __launch_bounds__(256) void lin2_kernel(
    const float* __restrict__ h, const float* __restrict__ Wl, const float* __restrict__ bl,
    const float* __restrict__ Wr, const float* __restrict__ br,
    float* __restrict__ hl, float* __restrict__ hr, int n) {
  __shared__ float hs[32][132];  // row stride 528B -> 16B-aligned float4 reads
  int r0 = blockIdx.x * 32;
  for (int i = threadIdx.x; i < 32 * 128; i += 256) {
    int r = i >> 7, c = i & 127;
    int gr = r0 + r;
    hs[r][c] = (gr < n) ? h[gr * 128 + c] : 0.f;
  }
  __syncthreads();
  int col = threadIdx.x & 127;
  int half = threadIdx.x >> 7;  // owns rows half*16 .. half*16+15
  float accl[16], accr[16];
  float bvl = bl[col], bvr = br[col];
#pragma unroll
  for (int i = 0; i < 16; i++) { accl[i] = bvl; accr[i] = bvr; }
  for (int k = 0; k < 128; k += 4) {
    float wl[4], wr[4];
#pragma unroll
    for (int kk = 0; kk < 4; kk++) {
      wl[kk] = Wl[(k + kk) * 128 + col];
      wr[kk] = Wr[(k + kk) * 128 + col];
    }
#pragma unroll
    for (int i = 0; i < 16; i++) {
      float4 hv = *(const float4*)&hs[half * 16 + i][k];
      accl[i] += hv.x * wl[0] + hv.y * wl[1] + hv.z * wl[2] + hv.w * wl[3];
      accr[i] += hv.x * wr[0] + hv.y * wr[1] + hv.z * wr[2] + hv.w * wr[3];
    }
  }
#pragma unroll
  for (int i = 0; i < 16; i++) {
    int gr = r0 + half * 16 + i;
    if (gr < n) {
      hl[gr * 128 + col] = accl[i];
      hr[gr * 128 + col] = accr[i];
    }
  }
}

// One wave per node. 4 edge-groups x 16 lanes (8 dims/lane). Online softmax per
// group; 2-level cross-group state merge at the end. Sentinel NEGM (-1e30)
// instead of -inf keeps exp2 differences finite (empty groups self-heal: their
// polluted s/acc are scaled by exp2(NEGM - real) = 0 in the merge).
__global__ __launch_bounds__(256) void attn_kernel(
    const float* __restrict__ hl, const float* __restrict__ hr,
    const uint* __restrict__ off, const uint* __restrict__ sorted,
    const uint* __restrict__ hist, const float* __restrict__ tab,
    const float* __restrict__ att, const float* __restrict__ bias,
    float* __restrict__ out, int n, int do_relu) {
  __shared__ float tabs[24][128];
  for (int i = threadIdx.x; i < 24 * 128; i += 256) tabs[i >> 7][i & 127] = tab[i];
  __syncthreads();
  int wave = threadIdx.x >> 6, lane = threadIdx.x & 63;
  int node = blockIdx.x * 4 + wave;
  if (node >= n) return;
  int g = lane >> 4;         // edge group 0..3
  int dq = (lane & 15) * 8;  // owned dims [dq, dq+8)

  const float* hrp = &hr[(size_t)node * 128 + dq];
  const float* hlp = &hl[(size_t)node * 128 + dq];
  float4 hr0 = *(const float4*)hrp, hr1 = *(const float4*)(hrp + 4);
  float4 hl0 = *(const float4*)hlp, hl1 = *(const float4*)(hlp + 4);
  float4 at0 = f4scale(*(const float4*)&att[dq], LOG2E);      // fold log2e: exp->exp2
  float4 at1 = f4scale(*(const float4*)&att[dq + 4], LOG2E);

  // self-loop edge projection = mean of incoming e_proj, via (feature,value) histogram
  float4 ep0 = make_float4(0.f, 0.f, 0.f, 0.f), ep1 = ep0;
  uint c = 0;
#pragma unroll
  for (int j = 0; j < 24; j++) {
    uint hc = hist[node * 24 + j];
    if (j < 8) c += hc;  // in-degree
    if (hc) {            // wave-uniform branch (hist is per-node)
      float f = (float)hc;
      ep0 = f4fma(f, *(const float4*)&tabs[j][dq], ep0);
      ep1 = f4fma(f, *(const float4*)&tabs[j][dq + 4], ep1);
    }
  }
  if (c) {
    float ic = 1.f / (float)c;
    ep0 = f4scale(ep0, ic);
    ep1 = f4scale(ep1, ic);
  }

  // 16-lane-group reduced score (log2 domain)
  auto redscore = [&](float4 z0, float4 z1) -> float {
    float p = lrelu_dot(z0, at0) + lrelu_dot(z1, at1);
    p += __shfl_xor(p, 1);
    p += __shfl_xor(p, 2);
    p += __shfl_xor(p, 4);
    p += __shfl_xor(p, 8);
    return p;
  };

  float sself = redscore(f4add(f4add(hl0, hr0), ep0), f4add(f4add(hl1, hr1), ep1));

  float m, s;
  float4 a0, a1;
  if (g == 0) {
    m = sself; s = 1.f; a0 = hl0; a1 = hl1;  // self-loop lives in group 0
  } else {
    m = NEGM; s = 0.f;
    a0 = make_float4(0.f, 0.f, 0.f, 0.f); a1 = a0;
  }

  uint e0 = off[node], e1 = off[node + 1];
  for (uint base = e0; base < e1; base += 8) {
    uint eA = base + (uint)g, eB = eA + 4u;
    uint iA = eA < e1 ? eA : e1 - 1;  // clamp; masked below
    uint iB = eB < e1 ? eB : e1 - 1;
    uint pkA = sorted[iA], pkB = sorted[iB];
    const float* pa = &hl[(size_t)(pkA & SRC_MASK) * 128 + dq];
    const float* pb = &hl[(size_t)(pkB & SRC_MASK) * 128 + dq];
    float4 hA0 = *(const float4*)pa, hA1 = *(const float4*)(pa + 4);
    float4 hB0 = *(const float4*)pb, hB1 = *(const float4*)(pb + 4);
    int a0A = (pkA >> 23) & 7, a1A = (pkA >> 26) & 7, a2A = (pkA >> 29) & 7;
    int a0B = (pkB >> 23) & 7, a1B = (pkB >> 26) & 7, a2B = (pkB >> 29) & 7;
    float4 eA0 = f4add(f4add(*(const float4*)&tabs[a0A][dq], *(const float4*)&tabs[8 + a1A][dq]),
                       *(const float4*)&tabs[16 + a2A][dq]);
    float4 eA1 = f4add(f4add(*(const float4*)&tabs[a0A][dq + 4],
                             *(const float4*)&tabs[8 + a1A][dq + 4]),
                       *(const float4*)&tabs[16 + a2A][dq + 4]);
    float4 eB0 = f4add(f4add(*(const float4*)&tabs[a0B][dq], *(const float4*)&tabs[8 + a1B][dq]),
                       *(const float4*)&tabs[16 + a2B][dq]);
    float4 eB1 = f4add(f4add(*(const float4*)&tabs[a0B][dq + 4],
                             *(const float4*)&tabs[8 + a1B][dq + 4]),
                       *(const float4*)&tabs[16 + a2B][dq + 4]);
    float scA = redscore(f4add(f4add(hA0, hr0), eA0), f4add(f4add(hA1, hr1), eA1));
    float scB = redscore(f4add(f4add(hB0, hr0), eB0), f4add(f4add(hB1, hr1), eB1));
    if (eA >= e1) scA = NEGM;
    if (eB >= e1) scB = NEGM;
    float mn = fmaxf(m, fmaxf(scA, scB));
    float corr = exp2f(m - mn);
    float pA = exp2f(scA - mn), pB = exp2f(scB - mn);
    s = s * corr + pA + pB;
    a0 = f4fma(pA, hA0, f4fma(pB, hB0, f4scale(a0, corr)));
    a1 = f4fma(pA, hA1, f4fma(pB, hB1, f4scale(a1, corr)));
    m = mn;
  }

  // merge the 4 group states (flash-style): xor 16, then xor 32
#pragma unroll
  for (int lvl = 16; lvl <= 32; lvl <<= 1) {
    float om = __shfl_xor(m, lvl);
    float os = __shfl_xor(s, lvl);
    float4 o0 = make_float4(__shfl_xor(a0.x, lvl), __shfl_xor(a0.y, lvl),
                            __shfl_xor(a0.z, lvl), __shfl_xor(a0.w, lvl));
    float4 o1 = make_float4(__shfl_xor(a1.x, lvl), __shfl_xor(a1.y, lvl),
                            __shfl_xor(a1.z, lvl), __shfl_xor(a1.w, lvl));
    float mn = fmaxf(m, om);
    float ca = exp2f(m - mn), cb = exp2f(om - mn);
    s = s * ca + os * cb;
    a0 = f4fma(cb, o0, f4scale(a0, ca));
    a1 = f4fma(cb, o1, f4scale(a1, ca));
    m = mn;
  }

  float inv = 1.f / s;
  float4 b0 = *(const float4*)&bias[dq], b1 = *(const float4*)&bias[dq + 4];
  float4 o0 = f4fma(inv, a0, b0);
  float4 o1 = f4fma(inv, a1, b1);
  if (do_relu) {
    o0 = f4relu(o0);
    o1 = f4relu(o1);
  }
  if (lane < 16) {  // one group writes the node's 128 dims
    *(float4*)&out[(size_t)node * 128 + dq] = o0;
    *(float4*)&out[(size_t)node * 128 + dq + 4] = o1;
  }
}

// batch is sorted: run-length accumulate, flush once per graph boundary per block-chunk.
#define POOL_CHUNK 128
__global__ void pool_kernel(const float* __restrict__ h, const int* __restrict__ batch,
                            float* __restrict__ pool, uint* __restrict__ cntg, int n) {
  int d = threadIdx.x;  // 128 threads
  int i0 = blockIdx.x * POOL_CHUNK;
  if (i0 >= n) return;
  int i1 = min(i0 + POOL_CHUNK, n);
  int g = batch[i0];
  float s = 0.f;
  uint c = 0;
  for (int i = i0; i < i1; i++) {
    int gi = batch[i];
    if (gi != g) {
      atomicAdd(&pool[g * 128 + d], s);
      if (d == 0) atomicAdd(&cntg[g], c);
      g = gi;
      s = 0.f;
      c = 0;
    }
    s += h[i * 128 + d];
    c++;
  }
  atomicAdd(&pool[g * 128 + d], s);
  if (d == 0) atomicAdd(&cntg[g], c);
}

__global__ void out_kernel(const float* __restrict__ pool, const uint* __restrict__ cntg,
                           const float* __restrict__ Wout, const float* __restrict__ bout,
                           float* __restrict__ out, int g_) {
  int wave = threadIdx.x >> 6, lane = threadIdx.x & 63;
  int g = blockIdx.x * 4 + wave;
  if (g >= g_) return;
  int d = lane * 2;
  float2 pv = *(const float2*)&pool[g * 128 + d];
  float2 wv = *(const float2*)&Wout[d];
  float p = pv.x * wv.x + pv.y * wv.y;
#pragma unroll
  for (int o = 32; o > 0; o >>= 1) p += __shfl_xor(p, o);
  if (lane == 0) {
    uint c = cntg[g];
    float cf = (float)(c ? c : 1u);
    float v = p / cf + bout[0];
    out[g] = 1.f / (1.f + expf(-v));
  }
}

extern "C" void kernel_launch(void* const* d_in, const int* in_sizes, int n_in,
                              void* d_out, int out_size, void* d_ws, size_t ws_size,
                              hipStream_t stream) {
  const int* x          = (const int*)d_in[0];
  const int* edge_index = (const int*)d_in[1];
  const int* edge_attr  = (const int*)d_in[2];
  const int* batch      = (const int*)d_in[3];
  const float* atom_emb = (const float*)d_in[4];
  const float* bond_emb = (const float*)d_in[5];
  const float* W1l = (const float*)d_in[6];
  const float* b1l = (const float*)d_in[7];
  const float* W1r = (const float*)d_in[8];
  const float* b1r = (const float*)d_in[9];
  const float* W1e = (const float*)d_in[10];
  const float* att1 = (const float*)d_in[11];
  const float* bias1 = (const float*)d_in[12];
  const float* W2l = (const float*)d_in[13];
  const float* b2l = (const float*)d_in[14];
  const float* W2r = (const float*)d_in[15];
  const float* b2r = (const float*)d_in[16];
  const float* W2e = (const float*)d_in[17];
  const float* att2 = (const float*)d_in[18];
  const float* bias2 = (const float*)d_in[19];
  const float* Wout = (const float*)d_in[20];
  const float* bout = (const float*)d_in[21];
  float* out = (float*)d_out;

  const int N = in_sizes[0] / 9;
  const int E = in_sizes[1] / 2;
  const int G = out_size;
  const int NB = (N + 1023) / 1024;  // scan blocks

  // workspace layout (3 big N*128 buffers: attn output overwrites lin2 input)
  char* w = (char*)d_ws;
  auto alloc = [&](size_t bytes) -> char* {
    char* p = w;
    w += (bytes + 255) & ~(size_t)255;
    return p;
  };
  float* h0     = (float*)alloc((size_t)N * 128 * 4);  // atom out / layer outs
  float* hl     = (float*)alloc((size_t)N * 128 * 4);
  float* hr     = (float*)alloc((size_t)N * 128 * 4);
  uint* off     = (uint*)alloc((size_t)(N + 1) * 4);
  uint* fill    = (uint*)alloc((size_t)N * 4);
  uint* hist    = (uint*)alloc((size_t)N * 24 * 4);
  uint* sorted  = (uint*)alloc((size_t)E * 4);
  float* tab1   = (float*)alloc(24 * 128 * 4);
  float* tab2   = (float*)alloc(24 * 128 * 4);
  float* pool   = (float*)alloc((size_t)G * 128 * 4);
  uint* cntg    = (uint*)alloc((size_t)G * 4);
  uint* bsum    = (uint*)alloc((size_t)NB * 4);
  uint* bpre    = (uint*)alloc((size_t)NB * 4);

  hipMemsetAsync(fill, 0, (size_t)N * 4, stream);
  hipMemsetAsync(hist, 0, (size_t)N * 24 * 4, stream);
  hipMemsetAsync(pool, 0, (size_t)G * 128 * 4, stream);
  hipMemsetAsync(cntg, 0, (size_t)G * 4, stream);

  table_kernel<<<48, 128, 0, stream>>>(bond_emb, W1e, W2e, tab1, tab2);
  atom_kernel<<<(N * 128 + THREADS - 1) / THREADS, THREADS, 0, stream>>>(x, atom_emb, h0, N);
  edge_hist_kernel<<<(E + THREADS - 1) / THREADS, THREADS, 0, stream>>>(edge_index, edge_attr,
                                                                        hist, E);
  scanA_kernel<<<NB, 256, 0, stream>>>(hist, off, bsum, N);
  scanB_kernel<<<1, 256, 0, stream>>>(bsum, bpre, NB);
  scanC_kernel<<<(N + THREADS - 1) / THREADS, THREADS, 0, stream>>>(off, bpre, N, E);
  scatter_kernel<<<(E + THREADS - 1) / THREADS, THREADS, 0, stream>>>(edge_index, edge_attr, off,
                                                                      fill, sorted, E);
  // layer 1
  lin2_kernel<<<(N + 31) / 32, 256, 0, stream>>>(h0, W1l, b1l, W1r, b1r, hl, hr, N);
  attn_kernel<<<(N + 3) / 4, 256, 0, stream>>>(hl, hr, off, sorted, hist, tab1, att1, bias1,
                                               h0, N, 1);
  // layer 2
  lin2_kernel<<<(N + 31) / 32, 256, 0, stream>>>(h0, W2l, b2l, W2r, b2r, hl, hr, N);
  attn_kernel<<<(N + 3) / 4, 256, 0, stream>>>(hl, hr, off, sorted, hist, tab2, att2, bias2,
                                               h0, N, 0);
  // readout
  pool_kernel<<<(N + POOL_CHUNK - 1) / POOL_CHUNK, 128, 0, stream>>>(h0, batch, pool, cntg, N);
  out_kernel<<<(G + 3) / 4, 256, 0, stream>>>(pool, cntg, Wout, bout, out, G);
}

// Round 12
// 707.495 us; speedup vs baseline: 1.1094x; 1.0286x over previous
//
#include <hip/hip_runtime.h>
#include <hip/hip_bf16.h>
#include <math.h>

// GATv2 (2 layers, D=128) + encoders + self-loops + mean-pool + sigmoid readout.
// attn v2.1: 4 edge-groups x 16 lanes; tabs rows padded to 132 floats so row j
// starts at bank 4j (was: all rows bank 0 -> 8-way conflict, 1.16e7 cycles/dispatch).
// lin2_atom: layer-1 linear fused with the atom-embedding encoder (no h0 roundtrip).

typedef unsigned int uint;

#define THREADS 256
#define LOG2E 1.4426950408889634f
#define NEGM -1e30f
// edge packing: src in bits [0,23), a0<<23, a1<<26, a2<<29
#define SRC_MASK 0x7fffffu
#define TPAD 132  // tabs row stride (floats): 528B -> bank stagger 4j, 16B-aligned

__device__ inline float4 f4add(float4 x, float4 y) {
  return make_float4(x.x + y.x, x.y + y.y, x.z + y.z, x.w + y.w);
}
__device__ inline float4 f4fma(float c, float4 x, float4 y) {  // c*x + y
  return make_float4(fmaf(c, x.x, y.x), fmaf(c, x.y, y.y), fmaf(c, x.z, y.z),
                     fmaf(c, x.w, y.w));
}
__device__ inline float4 f4scale(float4 x, float c) {
  return make_float4(x.x * c, x.y * c, x.z * c, x.w * c);
}
__device__ inline float lrelu_dot(float4 z, float4 a) {
  float r = (z.x > 0.f ? z.x : 0.2f * z.x) * a.x;
  r += (z.y > 0.f ? z.y : 0.2f * z.y) * a.y;
  r += (z.z > 0.f ? z.z : 0.2f * z.z) * a.z;
  r += (z.w > 0.f ? z.w : 0.2f * z.w) * a.w;
  return r;
}
__device__ inline float4 f4relu(float4 x) {
  return make_float4(fmaxf(x.x, 0.f), fmaxf(x.y, 0.f), fmaxf(x.z, 0.f), fmaxf(x.w, 0.f));
}

// hist[dst][f,v]++  (in-degree = sum of the first 8 bins; no separate cnt)
__global__ void edge_hist_kernel(const int* __restrict__ ei, const int* __restrict__ ea,
                                 uint* __restrict__ hist, int E_) {
  int e = blockIdx.x * blockDim.x + threadIdx.x;
  if (e >= E_) return;
  int dst = ei[E_ + e];
  int a0 = ea[e * 3 + 0], a1 = ea[e * 3 + 1], a2 = ea[e * 3 + 2];
  atomicAdd(&hist[dst * 24 + a0], 1u);
  atomicAdd(&hist[dst * 24 + 8 + a1], 1u);
  atomicAdd(&hist[dst * 24 + 16 + a2], 1u);
}

// ---- 3-phase exclusive scan of degree (= sum of hist bins 0..7) into off[0..n] ----
__global__ __launch_bounds__(256) void scanA_kernel(const uint* __restrict__ hist,
                                                    uint* __restrict__ off,
                                                    uint* __restrict__ bsum, int n) {
  __shared__ uint sc[256];
  int t = threadIdx.x;
  int base = blockIdx.x * 1024 + t * 4;
  uint v[4];
#pragma unroll
  for (int i = 0; i < 4; i++) {
    uint d = 0;
    int idx = base + i;
    if (idx < n) {
      const uint4* hp = (const uint4*)&hist[idx * 24];
      uint4 h0 = hp[0], h1 = hp[1];
      d = h0.x + h0.y + h0.z + h0.w + h1.x + h1.y + h1.z + h1.w;
    }
    v[i] = d;
  }
  uint s = v[0] + v[1] + v[2] + v[3];
  sc[t] = s;
  __syncthreads();
  for (int o = 1; o < 256; o <<= 1) {
    uint w = (t >= o) ? sc[t - o] : 0u;
    __syncthreads();
    sc[t] += w;
    __syncthreads();
  }
  uint r = sc[t] - s;
#pragma unroll
  for (int i = 0; i < 4; i++) {
    if (base + i < n) off[base + i] = r;
    r += v[i];
  }
  if (t == 255) bsum[blockIdx.x] = sc[t];
}

__global__ __launch_bounds__(256) void scanB_kernel(const uint* __restrict__ bsum,
                                                    uint* __restrict__ bpre, int nb) {
  __shared__ uint sc[256];
  int t = threadIdx.x;
  uint s = (t < nb) ? bsum[t] : 0u;
  sc[t] = s;
  __syncthreads();
  for (int o = 1; o < 256; o <<= 1) {
    uint w = (t >= o) ? sc[t - o] : 0u;
    __syncthreads();
    sc[t] += w;
    __syncthreads();
  }
  if (t < nb) bpre[t] = sc[t] - s;
}

__global__ void scanC_kernel(uint* __restrict__ off, const uint* __restrict__ bpre, int n,
                             int E_) {
  int i = blockIdx.x * blockDim.x + threadIdx.x;
  if (i < n) off[i] += bpre[i >> 10];
  if (i == 0) off[n] = (uint)E_;
}

__global__ void scatter_kernel(const int* __restrict__ ei, const int* __restrict__ ea,
                               const uint* __restrict__ off, uint* __restrict__ fill,
                               uint* __restrict__ sorted, int E_) {
  int e = blockIdx.x * blockDim.x + threadIdx.x;
  if (e >= E_) return;
  int src = ei[e], dst = ei[E_ + e];
  uint pos = off[dst] + atomicAdd(&fill[dst], 1u);
  uint pk = ((uint)src & SRC_MASK) | ((uint)ea[e * 3 + 0] << 23) |
            ((uint)ea[e * 3 + 1] << 26) | ((uint)ea[e * 3 + 2] << 29);
  sorted[pos] = pk;
}

// blocks 0..23: tab1[j] = bond_emb[j] @ W1e ; blocks 24..47: tab2[j-24] = bond_emb[j-24] @ W2e
__global__ void table_kernel(const float* __restrict__ bond_emb, const float* __restrict__ W1e,
                             const float* __restrict__ W2e, float* __restrict__ tab1,
                             float* __restrict__ tab2) {
  __shared__ float row[128];
  int b = blockIdx.x;
  int j = (b < 24) ? b : b - 24;
  const float* We = (b < 24) ? W1e : W2e;
  float* tab = (b < 24) ? tab1 : tab2;
  row[threadIdx.x] = bond_emb[j * 128 + threadIdx.x];
  __syncthreads();
  float acc = 0.f;
#pragma unroll 4
  for (int k = 0; k < 128; k++) acc += row[k] * We[k * 128 + threadIdx.x];
  tab[j * 128 + threadIdx.x] = acc;
}

// Layer 1: h built in-kernel from atom embeddings (fused encoder), then
// hl = h@Wl+bl ; hr = h@Wr+br. 32-row tile, 256 threads.
__global__ __launch_bounds__(256) void lin2_atom_kernel(
    const int* __restrict__ x, const float* __restrict__ atom_emb,
    const float* __restrict__ Wl, const float* __restrict__ bl,
    const float* __restrict__ Wr, const float* __restrict__ br,
    float* __restrict__ hl, float* __restrict__ hr, int n) {
  __shared__ float hs[32][132];
  int r0 = blockIdx.x * 32;
  int col = threadIdx.x & 127;
  int half = threadIdx.x >> 7;  // owns rows half*16 .. half*16+15
  for (int i = 0; i < 16; i++) {
    int r = half * 16 + i;
    int gr = r0 + r;
    float s = 0.f;
    if (gr < n) {
#pragma unroll
      for (int f = 0; f < 9; f++) {
        int v = x[gr * 9 + f];  // wave-broadcast load
        s += atom_emb[(f * 128 + v) * 128 + col];  // coalesced 512B row
      }
    }
    hs[r][col] = s;
  }
  __syncthreads();
  float accl[16], accr[16];
  float bvl = bl[col], bvr = br[col];
#pragma unroll
  for (int i = 0; i < 16; i++) { accl[i] = bvl; accr[i] = bvr; }
  for (int k = 0; k < 128; k += 4) {
    float wl[4], wr[4];
#pragma unroll
    for (int kk = 0; kk < 4; kk++) {
      wl[kk] = Wl[(k + kk) * 128 + col];
      wr[kk] = Wr[(k + kk) * 128 + col];
    }
#pragma unroll
    for (int i = 0; i < 16; i++) {
      float4 hv = *(const float4*)&hs[half * 16 + i][k];
      accl[i] += hv.x * wl[0] + hv.y * wl[1] + hv.z * wl[2] + hv.w * wl[3];
      accr[i] += hv.x * wr[0] + hv.y * wr[1] + hv.z * wr[2] + hv.w * wr[3];
    }
  }
#pragma unroll
  for (int i = 0; i < 16; i++) {
    int gr = r0 + half * 16 + i;
    if (gr < n) {
      hl[gr * 128 + col] = accl[i];
      hr[gr * 128 + col] = accr[i];
    }
  }
}

// hl = h@Wl+bl ; hr = h@Wr+br  — 32-row tile, 256 threads (layer 2, h from memory)
__global__ __launch_bounds__(256) void lin2_kernel(
    const float* __restrict__ h, const float* __restrict__ Wl, const float* __restrict__ bl,
    const float* __restrict__ Wr, const float* __restrict__ br,
    float* __restrict__ hl, float* __restrict__ hr, int n) {
  __shared__ float hs[32][132];  // row stride 528B -> 16B-aligned float4 reads
  int r0 = blockIdx.x * 32;
  for (int i = threadIdx.x; i < 32 * 128; i += 256) {
    int r = i >> 7, c = i & 127;
    int gr = r0 + r;
    hs[r][c] = (gr < n) ? h[gr * 128 + c] : 0.f;
  }
  __syncthreads();
  int col = threadIdx.x & 127;
  int half = threadIdx.x >> 7;  // owns rows half*16 .. half*16+15
  float accl[16], accr[16];
  float bvl = bl[col], bvr = br[col];
#pragma unroll
  for (int i = 0; i < 16; i++) { accl[i] = bvl; accr[i] = bvr; }
  for (int k = 0; k < 128; k += 4) {
    float wl[4], wr[4];
#pragma unroll
    for (int kk = 0; kk < 4; kk++) {
      wl[kk] = Wl[(k + kk) * 128 + col];
      wr[kk] = Wr[(k + kk) * 128 + col];
    }
#pragma unroll
    for (int i = 0; i < 16; i++) {
      float4 hv = *(const float4*)&hs[half * 16 + i][k];
      accl[i] += hv.x * wl[0] + hv.y * wl[1] + hv.z * wl[2] + hv.w * wl[3];
      accr[i] += hv.x * wr[0] + hv.y * wr[1] + hv.z * wr[2] + hv.w * wr[3];
    }
  }
#pragma unroll
  for (int i = 0; i < 16; i++) {
    int gr = r0 + half * 16 + i;
    if (gr < n) {
      hl[gr * 128 + col] = accl[i];
      hr[gr * 128 + col] = accr[i];
    }
  }
}

// One wave per node. 4 edge-groups x 16 lanes (8 dims/lane). Online softmax per
// group; 2-level cross-group state merge at the end. Sentinel NEGM (-1e30)
// keeps exp2 differences finite (empty groups self-heal in the merge).
// tabs rows padded to TPAD=132 floats: row j starts at bank 4j (conflict fix).
__global__ __launch_bounds__(256) void attn_kernel(
    const float* __restrict__ hl, const float* __restrict__ hr,
    const uint* __restrict__ off, const uint* __restrict__ sorted,
    const uint* __restrict__ hist, const float* __restrict__ tab,
    const float* __restrict__ att, const float* __restrict__ bias,
    float* __restrict__ out, int n, int do_relu) {
  __shared__ float tabs[24][TPAD];
  for (int i = threadIdx.x; i < 24 * 128; i += 256) tabs[i >> 7][i & 127] = tab[i];
  __syncthreads();
  int wave = threadIdx.x >> 6, lane = threadIdx.x & 63;
  int node = blockIdx.x * 4 + wave;
  if (node >= n) return;
  int g = lane >> 4;         // edge group 0..3
  int dq = (lane & 15) * 8;  // owned dims [dq, dq+8)

  const float* hrp = &hr[(size_t)node * 128 + dq];
  const float* hlp = &hl[(size_t)node * 128 + dq];
  float4 hr0 = *(const float4*)hrp, hr1 = *(const float4*)(hrp + 4);
  float4 hl0 = *(const float4*)hlp, hl1 = *(const float4*)(hlp + 4);
  float4 at0 = f4scale(*(const float4*)&att[dq], LOG2E);      // fold log2e: exp->exp2
  float4 at1 = f4scale(*(const float4*)&att[dq + 4], LOG2E);

  // self-loop edge projection = mean of incoming e_proj, via (feature,value) histogram
  float4 ep0 = make_float4(0.f, 0.f, 0.f, 0.f), ep1 = ep0;
  uint c = 0;
#pragma unroll
  for (int j = 0; j < 24; j++) {
    uint hc = hist[node * 24 + j];
    if (j < 8) c += hc;  // in-degree
    if (hc) {            // wave-uniform branch (hist is per-node)
      float f = (float)hc;
      ep0 = f4fma(f, *(const float4*)&tabs[j][dq], ep0);
      ep1 = f4fma(f, *(const float4*)&tabs[j][dq + 4], ep1);
    }
  }
  if (c) {
    float ic = 1.f / (float)c;
    ep0 = f4scale(ep0, ic);
    ep1 = f4scale(ep1, ic);
  }

  // 16-lane-group reduced score (log2 domain)
  auto redscore = [&](float4 z0, float4 z1) -> float {
    float p = lrelu_dot(z0, at0) + lrelu_dot(z1, at1);
    p += __shfl_xor(p, 1);
    p += __shfl_xor(p, 2);
    p += __shfl_xor(p, 4);
    p += __shfl_xor(p, 8);
    return p;
  };

  float sself = redscore(f4add(f4add(hl0, hr0), ep0), f4add(f4add(hl1, hr1), ep1));

  float m, s;
  float4 a0, a1;
  if (g == 0) {
    m = sself; s = 1.f; a0 = hl0; a1 = hl1;  // self-loop lives in group 0
  } else {
    m = NEGM; s = 0.f;
    a0 = make_float4(0.f, 0.f, 0.f, 0.f); a1 = a0;
  }

  uint e0 = off[node], e1 = off[node + 1];
  for (uint base = e0; base < e1; base += 8) {
    uint eA = base + (uint)g, eB = eA + 4u;
    uint iA = eA < e1 ? eA : e1 - 1;  // clamp; masked below
    uint iB = eB < e1 ? eB : e1 - 1;
    uint pkA = sorted[iA], pkB = sorted[iB];
    const float* pa = &hl[(size_t)(pkA & SRC_MASK) * 128 + dq];
    const float* pb = &hl[(size_t)(pkB & SRC_MASK) * 128 + dq];
    float4 hA0 = *(const float4*)pa, hA1 = *(const float4*)(pa + 4);
    float4 hB0 = *(const float4*)pb, hB1 = *(const float4*)(pb + 4);
    int a0A = (pkA >> 23) & 7, a1A = (pkA >> 26) & 7, a2A = (pkA >> 29) & 7;
    int a0B = (pkB >> 23) & 7, a1B = (pkB >> 26) & 7, a2B = (pkB >> 29) & 7;
    float4 eA0 = f4add(f4add(*(const float4*)&tabs[a0A][dq], *(const float4*)&tabs[8 + a1A][dq]),
                       *(const float4*)&tabs[16 + a2A][dq]);
    float4 eA1 = f4add(f4add(*(const float4*)&tabs[a0A][dq + 4],
                             *(const float4*)&tabs[8 + a1A][dq + 4]),
                       *(const float4*)&tabs[16 + a2A][dq + 4]);
    float4 eB0 = f4add(f4add(*(const float4*)&tabs[a0B][dq], *(const float4*)&tabs[8 + a1B][dq]),
                       *(const float4*)&tabs[16 + a2B][dq]);
    float4 eB1 = f4add(f4add(*(const float4*)&tabs[a0B][dq + 4],
                             *(const float4*)&tabs[8 + a1B][dq + 4]),
                       *(const float4*)&tabs[16 + a2B][dq + 4]);
    float scA = redscore(f4add(f4add(hA0, hr0), eA0), f4add(f4add(hA1, hr1), eA1));
    float scB = redscore(f4add(f4add(hB0, hr0), eB0), f4add(f4add(hB1, hr1), eB1));
    if (eA >= e1) scA = NEGM;
    if (eB >= e1) scB = NEGM;
    float mn = fmaxf(m, fmaxf(scA, scB));
    float corr = exp2f(m - mn);
    float pA = exp2f(scA - mn), pB = exp2f(scB - mn);
    s = s * corr + pA + pB;
    a0 = f4fma(pA, hA0, f4fma(pB, hB0, f4scale(a0, corr)));
    a1 = f4fma(pA, hA1, f4fma(pB, hB1, f4scale(a1, corr)));
    m = mn;
  }

  // merge the 4 group states (flash-style): xor 16, then xor 32
#pragma unroll
  for (int lvl = 16; lvl <= 32; lvl <<= 1) {
    float om = __shfl_xor(m, lvl);
    float os = __shfl_xor(s, lvl);
    float4 o0 = make_float4(__shfl_xor(a0.x, lvl), __shfl_xor(a0.y, lvl),
                            __shfl_xor(a0.z, lvl), __shfl_xor(a0.w, lvl));
    float4 o1 = make_float4(__shfl_xor(a1.x, lvl), __shfl_xor(a1.y, lvl),
                            __shfl_xor(a1.z, lvl), __shfl_xor(a1.w, lvl));
    float mn = fmaxf(m, om);
    float ca = exp2f(m - mn), cb = exp2f(om - mn);
    s = s * ca + os * cb;
    a0 = f4fma(cb, o0, f4scale(a0, ca));
    a1 = f4fma(cb, o1, f4scale(a1, ca));
    m = mn;
  }

  float inv = 1.f / s;
  float4 b0 = *(const float4*)&bias[dq], b1 = *(const float4*)&bias[dq + 4];
  float4 o0 = f4fma(inv, a0, b0);
  float4 o1 = f4fma(inv, a1, b1);
  if (do_relu) {
    o0 = f4relu(o0);
    o1 = f4relu(o1);
  }
  if (lane < 16) {  // one group writes the node's 128 dims
    *(float4*)&out[(size_t)node * 128 + dq] = o0;
    *(float4*)&out[(size_t)node * 128 + dq + 4] = o1;
  }
}

// batch is sorted: run-length accumulate, flush once per graph boundary per block-chunk.
#define POOL_CHUNK 128
__global__ void pool_kernel(const float* __restrict__ h, const int* __restrict__ batch,
                            float* __restrict__ pool, uint* __restrict__ cntg, int n) {
  int d = threadIdx.x;  // 128 threads
  int i0 = blockIdx.x * POOL_CHUNK;
  if (i0 >= n) return;
  int i1 = min(i0 + POOL_CHUNK, n);
  int g = batch[i0];
  float s = 0.f;
  uint c = 0;
  for (int i = i0; i < i1; i++) {
    int gi = batch[i];
    if (gi != g) {
      atomicAdd(&pool[g * 128 + d], s);
      if (d == 0) atomicAdd(&cntg[g], c);
      g = gi;
      s = 0.f;
      c = 0;
    }
    s += h[i * 128 + d];
    c++;
  }
  atomicAdd(&pool[g * 128 + d], s);
  if (d == 0) atomicAdd(&cntg[g], c);
}

__global__ void out_kernel(const float* __restrict__ pool, const uint* __restrict__ cntg,
                           const float* __restrict__ Wout, const float* __restrict__ bout,
                           float* __restrict__ out, int g_) {
  int wave = threadIdx.x >> 6, lane = threadIdx.x & 63;
  int g = blockIdx.x * 4 + wave;
  if (g >= g_) return;
  int d = lane * 2;
  float2 pv = *(const float2*)&pool[g * 128 + d];
  float2 wv = *(const float2*)&Wout[d];
  float p = pv.x * wv.x + pv.y * wv.y;
#pragma unroll
  for (int o = 32; o > 0; o >>= 1) p += __shfl_xor(p, o);
  if (lane == 0) {
    uint c = cntg[g];
    float cf = (float)(c ? c : 1u);
    float v = p / cf + bout[0];
    out[g] = 1.f / (1.f + expf(-v));
  }
}

extern "C" void kernel_launch(void* const* d_in, const int* in_sizes, int n_in,
                              void* d_out, int out_size, void* d_ws, size_t ws_size,
                              hipStream_t stream) {
  const int* x          = (const int*)d_in[0];
  const int* edge_index = (const int*)d_in[1];
  const int* edge_attr  = (const int*)d_in[2];
  const int* batch      = (const int*)d_in[3];
  const float* atom_emb = (const float*)d_in[4];
  const float* bond_emb = (const float*)d_in[5];
  const float* W1l = (const float*)d_in[6];
  const float* b1l = (const float*)d_in[7];
  const float* W1r = (const float*)d_in[8];
  const float* b1r = (const float*)d_in[9];
  const float* W1e = (const float*)d_in[10];
  const float* att1 = (const float*)d_in[11];
  const float* bias1 = (const float*)d_in[12];
  const float* W2l = (const float*)d_in[13];
  const float* b2l = (const float*)d_in[14];
  const float* W2r = (const float*)d_in[15];
  const float* b2r = (const float*)d_in[16];
  const float* W2e = (const float*)d_in[17];
  const float* att2 = (const float*)d_in[18];
  const float* bias2 = (const float*)d_in[19];
  const float* Wout = (const float*)d_in[20];
  const float* bout = (const float*)d_in[21];
  float* out = (float*)d_out;

  const int N = in_sizes[0] / 9;
  const int E = in_sizes[1] / 2;
  const int G = out_size;
  const int NB = (N + 1023) / 1024;  // scan blocks

  // workspace layout (3 big N*128 buffers: attn output overwrites lin2 input)
  char* w = (char*)d_ws;
  auto alloc = [&](size_t bytes) -> char* {
    char* p = w;
    w += (bytes + 255) & ~(size_t)255;
    return p;
  };
  float* h0     = (float*)alloc((size_t)N * 128 * 4);  // layer-1/2 activations
  float* hl     = (float*)alloc((size_t)N * 128 * 4);
  float* hr     = (float*)alloc((size_t)N * 128 * 4);
  uint* off     = (uint*)alloc((size_t)(N + 1) * 4);
  uint* fill    = (uint*)alloc((size_t)N * 4);
  uint* hist    = (uint*)alloc((size_t)N * 24 * 4);
  uint* sorted  = (uint*)alloc((size_t)E * 4);
  float* tab1   = (float*)alloc(24 * 128 * 4);
  float* tab2   = (float*)alloc(24 * 128 * 4);
  float* pool   = (float*)alloc((size_t)G * 128 * 4);
  uint* cntg    = (uint*)alloc((size_t)G * 4);
  uint* bsum    = (uint*)alloc((size_t)NB * 4);
  uint* bpre    = (uint*)alloc((size_t)NB * 4);

  hipMemsetAsync(fill, 0, (size_t)N * 4, stream);
  hipMemsetAsync(hist, 0, (size_t)N * 24 * 4, stream);
  hipMemsetAsync(pool, 0, (size_t)G * 128 * 4, stream);
  hipMemsetAsync(cntg, 0, (size_t)G * 4, stream);

  table_kernel<<<48, 128, 0, stream>>>(bond_emb, W1e, W2e, tab1, tab2);
  edge_hist_kernel<<<(E + THREADS - 1) / THREADS, THREADS, 0, stream>>>(edge_index, edge_attr,
                                                                        hist, E);
  scanA_kernel<<<NB, 256, 0, stream>>>(hist, off, bsum, N);
  scanB_kernel<<<1, 256, 0, stream>>>(bsum, bpre, NB);
  scanC_kernel<<<(N + THREADS - 1) / THREADS, THREADS, 0, stream>>>(off, bpre, N, E);
  scatter_kernel<<<(E + THREADS - 1) / THREADS, THREADS, 0, stream>>>(edge_index, edge_attr, off,
                                                                      fill, sorted, E);
  // layer 1 (atom encoder fused into the linear)
  lin2_atom_kernel<<<(N + 31) / 32, 256, 0, stream>>>(x, atom_emb, W1l, b1l, W1r, b1r, hl, hr, N);
  attn_kernel<<<(N + 3) / 4, 256, 0, stream>>>(hl, hr, off, sorted, hist, tab1, att1, bias1,
                                               h0, N, 1);
  // layer 2
  lin2_kernel<<<(N + 31) / 32, 256, 0, stream>>>(h0, W2l, b2l, W2r, b2r, hl, hr, N);
  attn_kernel<<<(N + 3) / 4, 256, 0, stream>>>(hl, hr, off, sorted, hist, tab2, att2, bias2,
                                               h0, N, 0);
  // readout
  pool_kernel<<<(N + POOL_CHUNK - 1) / POOL_CHUNK, 128, 0, stream>>>(h0, batch, pool, cntg, N);
  out_kernel<<<(G + 3) / 4, 256, 0, stream>>>(pool, cntg, Wout, bout, out, G);
}